// Round 1
// baseline (613.952 us; speedup 1.0000x reference)
//
#include <hip/hip_runtime.h>
#include <math.h>

#define BN_EPS 1e-5f

static constexpr int BB = 16;    // batch
static constexpr int C  = 512;   // channels
static constexpr int NP = 1024;  // pixels H*W
static constexpr int NH = 8;     // heads
static constexpr int HD = 64;    // head dim

// ws layout (bytes)
static constexpr size_t OFF_Q  = 0;                       // int8  [16][512][1024]
static constexpr size_t OFF_K  = 8388608;                 // int8  [16][512][1024]
static constexpr size_t OFF_V  = 16777216;                // f32   [16][512][1024]
static constexpr size_t OFF_AO = 50331648;                // f32   [16][512][1024]
static constexpr size_t OFF_P  = 83886080;                // f32   [16][8][64][64]

// ---------------------------------------------------------------------------
// Kernel 1: fused qkv 1x1-conv GEMM (fp32) + BatchNorm + ternary sign for q,k
// per batch b: [1536x512] W  x  [512x1024] X.  128x128x16 tile, 256 thr, 8x8.
// ---------------------------------------------------------------------------
__global__ __launch_bounds__(256, 2) void k_qkv(
    const float* __restrict__ W, const float* __restrict__ X,
    const float* __restrict__ g, const float* __restrict__ be,
    const float* __restrict__ mu, const float* __restrict__ va,
    signed char* __restrict__ qw, signed char* __restrict__ kw,
    float* __restrict__ vw)
{
  const int t = threadIdx.x;
  const int tx = t & 15, ty = t >> 4;
  const int n0 = blockIdx.x * 128;
  const int m0 = blockIdx.y * 128;
  const int b  = blockIdx.z;

  __shared__ float As[16][128];
  __shared__ float Bs[16][128];

  float acc[8][8];
#pragma unroll
  for (int i = 0; i < 8; ++i)
#pragma unroll
    for (int j = 0; j < 8; ++j) acc[i][j] = 0.f;

  const float* Wp = W + (size_t)m0 * 512;
  const float* Xp = X + (size_t)b * C * NP + n0;

  const int arow = t >> 1, acol = (t & 1) * 8;
  const int brow = t >> 5, bcol = (t & 31) * 4;

  for (int kc = 0; kc < 512; kc += 16) {
    float4 a0 = *(const float4*)(Wp + (size_t)arow * 512 + kc + acol);
    float4 a1 = *(const float4*)(Wp + (size_t)arow * 512 + kc + acol + 4);
    float4 b0 = *(const float4*)(Xp + (size_t)(kc + brow) * NP + bcol);
    float4 b1 = *(const float4*)(Xp + (size_t)(kc + brow + 8) * NP + bcol);
    __syncthreads();
    As[acol + 0][arow] = a0.x; As[acol + 1][arow] = a0.y;
    As[acol + 2][arow] = a0.z; As[acol + 3][arow] = a0.w;
    As[acol + 4][arow] = a1.x; As[acol + 5][arow] = a1.y;
    As[acol + 6][arow] = a1.z; As[acol + 7][arow] = a1.w;
    *(float4*)&Bs[brow][bcol] = b0;
    *(float4*)&Bs[brow + 8][bcol] = b1;
    __syncthreads();
#pragma unroll
    for (int kk = 0; kk < 16; ++kk) {
      float af[8], bf[8];
      *(float4*)(af + 0) = *(const float4*)&As[kk][ty * 8];
      *(float4*)(af + 4) = *(const float4*)&As[kk][ty * 8 + 4];
      *(float4*)(bf + 0) = *(const float4*)&Bs[kk][tx * 8];
      *(float4*)(bf + 4) = *(const float4*)&Bs[kk][tx * 8 + 4];
#pragma unroll
      for (int i = 0; i < 8; ++i)
#pragma unroll
        for (int j = 0; j < 8; ++j)
          acc[i][j] = fmaf(af[i], bf[j], acc[i][j]);
    }
  }

  const int kidx = m0 >> 9;       // 0=q 1=k 2=v (128-tiles never cross 512)
  const int obase = m0 & 511;
#pragma unroll
  for (int i = 0; i < 8; ++i) {
    const int o = obase + ty * 8 + i;
    const int ch = (kidx << 9) + o;
    const float s  = g[ch] / sqrtf(va[ch] + BN_EPS);
    const float bb = be[ch] - mu[ch] * s;
    const size_t base = ((size_t)b * C + o) * NP + n0 + tx * 8;
    if (kidx == 2) {
#pragma unroll
      for (int j = 0; j < 8; ++j) vw[base + j] = fmaf(acc[i][j], s, bb);
    } else {
      signed char* dst = (kidx == 0) ? qw : kw;
#pragma unroll
      for (int j = 0; j < 8; ++j) {
        const float y = fmaf(acc[i][j], s, bb);
        dst[base + j] = (signed char)((y > 0.f) - (y < 0.f));
      }
    }
  }
}

// ---------------------------------------------------------------------------
// Kernel 2: per (b,h): attn logits S = q.k^T (exact int sums in fp32),
// softmax over e with scale 1/8 (exact power-of-two), write P [64][64].
// ---------------------------------------------------------------------------
__global__ __launch_bounds__(256) void k_attn(
    const signed char* __restrict__ qw, const signed char* __restrict__ kw,
    float* __restrict__ P)
{
  const int bh = blockIdx.x;          // 0..127
  const int b = bh >> 3, h = bh & 7;
  const int t = threadIdx.x;
  const int tx = t & 15, ty = t >> 4; // each thread: 4x4 of the 64x64 logits
  const int d0 = ty * 4, e0 = tx * 4;

  __shared__ float qs[64][65];
  __shared__ float ks[64][65];
  __shared__ float sa[64][65];

  const signed char* qp = qw + ((size_t)b * C + h * HD) * NP;
  const signed char* kp = kw + ((size_t)b * C + h * HD) * NP;

  float acc[4][4];
#pragma unroll
  for (int i = 0; i < 4; ++i)
#pragma unroll
    for (int j = 0; j < 4; ++j) acc[i][j] = 0.f;

  const int lrow = t >> 2;            // 0..63
  const int lcol = (t & 3) * 16;      // 16B per thread

  for (int c0 = 0; c0 < NP; c0 += 64) {
    int4 qv = *(const int4*)(qp + (size_t)lrow * NP + c0 + lcol);
    int4 kv = *(const int4*)(kp + (size_t)lrow * NP + c0 + lcol);
    __syncthreads();
    const signed char* qb = (const signed char*)&qv;
    const signed char* kb = (const signed char*)&kv;
#pragma unroll
    for (int i = 0; i < 16; ++i) {
      qs[lrow][lcol + i] = (float)qb[i];
      ks[lrow][lcol + i] = (float)kb[i];
    }
    __syncthreads();
#pragma unroll 4
    for (int n = 0; n < 64; ++n) {
      float qa[4], kx[4];
#pragma unroll
      for (int i = 0; i < 4; ++i) qa[i] = qs[d0 + i][n];
#pragma unroll
      for (int j = 0; j < 4; ++j) kx[j] = ks[e0 + j][n];
#pragma unroll
      for (int i = 0; i < 4; ++i)
#pragma unroll
        for (int j = 0; j < 4; ++j)
          acc[i][j] = fmaf(qa[i], kx[j], acc[i][j]);
    }
  }
  __syncthreads();
#pragma unroll
  for (int i = 0; i < 4; ++i)
#pragma unroll
    for (int j = 0; j < 4; ++j) sa[d0 + i][e0 + j] = acc[i][j];
  __syncthreads();

  if (t < 64) {
    float mx = -1e30f;
#pragma unroll 8
    for (int e = 0; e < 64; ++e) mx = fmaxf(mx, sa[t][e]);
    float sum = 0.f;
#pragma unroll 8
    for (int e = 0; e < 64; ++e) {
      const float p = expf((sa[t][e] - mx) * 0.125f);
      sa[t][e] = p;
      sum += p;
    }
    const float inv = 1.f / sum;
    float* Pp = P + (size_t)bh * HD * HD + (size_t)t * HD;
#pragma unroll 8
    for (int e = 0; e < 64; ++e) Pp[e] = sa[t][e] * inv;
  }
}

// ---------------------------------------------------------------------------
// Kernel 3: PV. block = (n-chunk of 256, bh). thread owns column n,
// keeps v[0..63][n] in regs, out[d][n] = sum_e P[d][e] * v[e][n].
// ---------------------------------------------------------------------------
__global__ __launch_bounds__(256) void k_pv(
    const float* __restrict__ P, const float* __restrict__ vw,
    float* __restrict__ ao)
{
  const int nc = blockIdx.x;          // 0..3
  const int bh = blockIdx.y;          // 0..127
  const int b = bh >> 3, h = bh & 7;
  const int t = threadIdx.x;

  __shared__ float ps[64][64];
  const float* Pp = P + (size_t)bh * HD * HD;
  for (int i = t; i < HD * HD; i += 256) ((float*)ps)[i] = Pp[i];
  __syncthreads();

  const int n = nc * 256 + t;
  const float* vp = vw + ((size_t)b * C + h * HD) * NP + n;
  float vr[64];
#pragma unroll
  for (int e = 0; e < HD; ++e) vr[e] = vp[(size_t)e * NP];

  float* aop = ao + ((size_t)b * C + h * HD) * NP + n;
  for (int d = 0; d < HD; ++d) {
    float s = 0.f;
#pragma unroll
    for (int e = 0; e < HD; ++e) s = fmaf(ps[d][e], vr[e], s);
    aop[(size_t)d * NP] = s;
  }
}

// ---------------------------------------------------------------------------
// Kernel 4: proj GEMM (fp32) + residual.  per b: [512x512] x [512x1024].
// ---------------------------------------------------------------------------
__global__ __launch_bounds__(256, 2) void k_proj(
    const float* __restrict__ W, const float* __restrict__ ao,
    const float* __restrict__ X, float* __restrict__ out)
{
  const int t = threadIdx.x;
  const int tx = t & 15, ty = t >> 4;
  const int n0 = blockIdx.x * 128;
  const int m0 = blockIdx.y * 128;
  const int b  = blockIdx.z;

  __shared__ float As[16][128];
  __shared__ float Bs[16][128];

  float acc[8][8];
#pragma unroll
  for (int i = 0; i < 8; ++i)
#pragma unroll
    for (int j = 0; j < 8; ++j) acc[i][j] = 0.f;

  const float* Wp = W + (size_t)m0 * 512;
  const float* Xp = ao + (size_t)b * C * NP + n0;

  const int arow = t >> 1, acol = (t & 1) * 8;
  const int brow = t >> 5, bcol = (t & 31) * 4;

  for (int kc = 0; kc < 512; kc += 16) {
    float4 a0 = *(const float4*)(Wp + (size_t)arow * 512 + kc + acol);
    float4 a1 = *(const float4*)(Wp + (size_t)arow * 512 + kc + acol + 4);
    float4 b0 = *(const float4*)(Xp + (size_t)(kc + brow) * NP + bcol);
    float4 b1 = *(const float4*)(Xp + (size_t)(kc + brow + 8) * NP + bcol);
    __syncthreads();
    As[acol + 0][arow] = a0.x; As[acol + 1][arow] = a0.y;
    As[acol + 2][arow] = a0.z; As[acol + 3][arow] = a0.w;
    As[acol + 4][arow] = a1.x; As[acol + 5][arow] = a1.y;
    As[acol + 6][arow] = a1.z; As[acol + 7][arow] = a1.w;
    *(float4*)&Bs[brow][bcol] = b0;
    *(float4*)&Bs[brow + 8][bcol] = b1;
    __syncthreads();
#pragma unroll
    for (int kk = 0; kk < 16; ++kk) {
      float af[8], bf[8];
      *(float4*)(af + 0) = *(const float4*)&As[kk][ty * 8];
      *(float4*)(af + 4) = *(const float4*)&As[kk][ty * 8 + 4];
      *(float4*)(bf + 0) = *(const float4*)&Bs[kk][tx * 8];
      *(float4*)(bf + 4) = *(const float4*)&Bs[kk][tx * 8 + 4];
#pragma unroll
      for (int i = 0; i < 8; ++i)
#pragma unroll
        for (int j = 0; j < 8; ++j)
          acc[i][j] = fmaf(af[i], bf[j], acc[i][j]);
    }
  }

#pragma unroll
  for (int i = 0; i < 8; ++i) {
    const int o = m0 + ty * 8 + i;
    const size_t base = ((size_t)b * C + o) * NP + n0 + tx * 8;
#pragma unroll
    for (int j = 0; j < 8; ++j) out[base + j] = acc[i][j] + X[base + j];
  }
}

// ---------------------------------------------------------------------------
extern "C" void kernel_launch(void* const* d_in, const int* in_sizes, int n_in,
                              void* d_out, int out_size, void* d_ws, size_t ws_size,
                              hipStream_t stream)
{
  const float* x      = (const float*)d_in[0];
  const float* w_qkv  = (const float*)d_in[1];
  const float* w_proj = (const float*)d_in[2];
  const float* g      = (const float*)d_in[3];
  const float* be     = (const float*)d_in[4];
  const float* mu     = (const float*)d_in[5];
  const float* va     = (const float*)d_in[6];
  float* out = (float*)d_out;

  char* ws = (char*)d_ws;
  signed char* qw = (signed char*)(ws + OFF_Q);
  signed char* kw = (signed char*)(ws + OFF_K);
  float* vw = (float*)(ws + OFF_V);
  float* ao = (float*)(ws + OFF_AO);
  float* P  = (float*)(ws + OFF_P);

  k_qkv <<<dim3(NP / 128, 3 * C / 128, BB), 256, 0, stream>>>(
      w_qkv, x, g, be, mu, va, qw, kw, vw);
  k_attn<<<dim3(BB * NH), 256, 0, stream>>>(qw, kw, P);
  k_pv  <<<dim3(NP / 256, BB * NH), 256, 0, stream>>>(P, vw, ao);
  k_proj<<<dim3(NP / 128, C / 128, BB), 256, 0, stream>>>(w_proj, ao, x, out);
}

// Round 2
// 282.507 us; speedup vs baseline: 2.1732x; 2.1732x over previous
//
#include <hip/hip_runtime.h>
#include <math.h>

#define BN_EPS 1e-5f

typedef _Float16 f16;
typedef _Float16 f16x8 __attribute__((ext_vector_type(8)));
typedef float f32x4 __attribute__((ext_vector_type(4)));

static constexpr int BB = 16;    // batch
static constexpr int C  = 512;   // channels
static constexpr int NP = 1024;  // pixels H*W
static constexpr int NH = 8;     // heads
static constexpr int HD = 64;    // head dim
static constexpr int M3 = 1536;  // 3*C

// ---- workspace layout (bytes) ----
static constexpr size_t OFF_WHI = 0;          // f16 [1536][512]
static constexpr size_t OFF_WLO = 1572864;    // f16 [1536][512]
static constexpr size_t OFF_WPH = 3145728;    // f16 [512][512]
static constexpr size_t OFF_SB  = 3670016;    // f32 s[1536], b[1536]
static constexpr size_t OFF_XTH = 3682304;    // f16 [16][1024][512]  (x transposed, hi)
static constexpr size_t OFF_XTL = 20459520;   // f16 [16][1024][512]  (lo)
static constexpr size_t OFF_AOT = OFF_XTH;    // f16 [16][1024][512]  (aliases XTH; XT dead after qkv)
static constexpr size_t OFF_Q   = 37236736;   // i8  [16][512][1024]
static constexpr size_t OFF_K   = 45625344;   // i8  [16][512][1024]
static constexpr size_t OFF_V   = 54013952;   // f16 [16][512][1024]
static constexpr size_t OFF_P   = 70791168;   // f32 [16][8][64][64]

__device__ __forceinline__ void gld16(const void* g, void* l) {
  __builtin_amdgcn_global_load_lds(
      (const __attribute__((address_space(1))) void*)g,
      (__attribute__((address_space(3))) void*)l, 16, 0, 0);
}

// ---------------------------------------------------------------------------
// conv W: fp32 -> f16 hi/lo (qkv), f16 hi (proj), and BN scale/bias arrays
// ---------------------------------------------------------------------------
__global__ __launch_bounds__(256) void k_convW(
    const float* __restrict__ wqkv, const float* __restrict__ wproj,
    const float* __restrict__ g, const float* __restrict__ be,
    const float* __restrict__ mu, const float* __restrict__ va,
    f16* __restrict__ Whi, f16* __restrict__ Wlo, f16* __restrict__ Wph,
    float* __restrict__ sA, float* __restrict__ bA)
{
  const int i = blockIdx.x * 256 + threadIdx.x;
  if (i < M3 * C) {
    const float w = wqkv[i];
    const f16 h = (f16)w;
    Whi[i] = h;
    Wlo[i] = (f16)(w - (float)h);
  }
  if (i < C * C) Wph[i] = (f16)wproj[i];
  if (i < M3) {
    const float s = g[i] / sqrtf(va[i] + BN_EPS);
    sA[i] = s;
    bA[i] = be[i] - mu[i] * s;
  }
}

// ---------------------------------------------------------------------------
// conv X: fp32 [b][k=512][n=1024] -> f16 hi/lo transposed [b][n][k]
// ---------------------------------------------------------------------------
__global__ __launch_bounds__(256) void k_convX(
    const float* __restrict__ x, f16* __restrict__ XtH, f16* __restrict__ XtL)
{
  const int k0 = blockIdx.x * 64, n0 = blockIdx.y * 64, b = blockIdx.z;
  __shared__ float ls[64][65];
  const int t = threadIdx.x;
  const float* xp = x + ((size_t)b * C + k0) * NP + n0;
  const int c4 = (t & 15) * 4, r0 = t >> 4;
#pragma unroll
  for (int q = 0; q < 4; ++q) {
    const float4 v = *(const float4*)(xp + (size_t)(r0 + q * 16) * NP + c4);
    ls[r0 + q * 16][c4 + 0] = v.x; ls[r0 + q * 16][c4 + 1] = v.y;
    ls[r0 + q * 16][c4 + 2] = v.z; ls[r0 + q * 16][c4 + 3] = v.w;
  }
  __syncthreads();
  const int n = t >> 2, kk = (t & 3) * 16;
  f16x8 hv0 = {}, hv1 = {}, lv0 = {}, lv1 = {};
#pragma unroll
  for (int q = 0; q < 8; ++q) {
    float v = ls[kk + q][n];
    f16 h = (f16)v;
    hv0[q] = h; lv0[q] = (f16)(v - (float)h);
  }
#pragma unroll
  for (int q = 0; q < 8; ++q) {
    float v = ls[kk + 8 + q][n];
    f16 h = (f16)v;
    hv1[q] = h; lv1[q] = (f16)(v - (float)h);
  }
  const size_t o = ((size_t)b * NP + n0 + n) * C + k0 + kk;
  *(f16x8*)&XtH[o] = hv0; *(f16x8*)&XtH[o + 8] = hv1;
  *(f16x8*)&XtL[o] = lv0; *(f16x8*)&XtL[o + 8] = lv1;
}

// ---------------------------------------------------------------------------
// qkv GEMM, 2-split f16 MFMA (3 products). Per b: [1536x512]x[512x1024].
// 128x128 tile, 4 waves (2x2), 4x4 16x16x32 frags/wave, BK=32.
// Epilogue: BN, then sign->i8 (q,k) or f16 (v).
// ---------------------------------------------------------------------------
__global__ __launch_bounds__(256) void k_qkv_mfma(
    const f16* __restrict__ Whi, const f16* __restrict__ Wlo,
    const f16* __restrict__ XtH, const f16* __restrict__ XtL,
    const float* __restrict__ sA, const float* __restrict__ bA,
    signed char* __restrict__ qw, signed char* __restrict__ kw,
    f16* __restrict__ vw)
{
  __shared__ __align__(16) f16 Ah[128 * 32];
  __shared__ __align__(16) f16 Al[128 * 32];
  __shared__ __align__(16) f16 Bh[128 * 32];
  __shared__ __align__(16) f16 Bl[128 * 32];

  const int t = threadIdx.x, lane = t & 63, wid = t >> 6;
  const int n0 = blockIdx.x * 128, m0 = blockIdx.y * 128, b = blockIdx.z;

  const f16* A0h = Whi + (size_t)m0 * C;
  const f16* A0l = Wlo + (size_t)m0 * C;
  const f16* B0h = XtH + ((size_t)b * NP + n0) * C;
  const f16* B0l = XtL + ((size_t)b * NP + n0) * C;

  f32x4 acc[4][4];
#pragma unroll
  for (int i = 0; i < 4; ++i)
#pragma unroll
    for (int j = 0; j < 4; ++j) acc[i][j] = (f32x4){0.f, 0.f, 0.f, 0.f};

  const int wm = wid >> 1, wn = wid & 1;
  const int lr = lane & 15, ls = lane >> 4;
  const int srow = wid * 16 + (lane >> 2);   // staging row (within 64-row round)
  const int scol = (lane & 3) * 8;           // staging col (f16 elems)

  for (int kc = 0; kc < 512; kc += 32) {
#pragma unroll
    for (int r = 0; r < 2; ++r) {
      const size_t go = (size_t)(r * 64 + srow) * C + kc + scol;
      const int lo = (r * 64 + wid * 16) * 32;   // wave-uniform LDS base (elems)
      gld16(A0h + go, &Ah[lo]);
      gld16(A0l + go, &Al[lo]);
      gld16(B0h + go, &Bh[lo]);
      gld16(B0l + go, &Bl[lo]);
    }
    __syncthreads();

    f16x8 ah[4], al[4], bh[4], bl[4];
#pragma unroll
    for (int i = 0; i < 4; ++i) {
      const int ao = (wm * 64 + i * 16 + lr) * 32 + ls * 8;
      ah[i] = *(const f16x8*)&Ah[ao];
      al[i] = *(const f16x8*)&Al[ao];
      const int bo = (wn * 64 + i * 16 + lr) * 32 + ls * 8;
      bh[i] = *(const f16x8*)&Bh[bo];
      bl[i] = *(const f16x8*)&Bl[bo];
    }
#pragma unroll
    for (int i = 0; i < 4; ++i)
#pragma unroll
      for (int j = 0; j < 4; ++j) {
        acc[i][j] = __builtin_amdgcn_mfma_f32_16x16x32_f16(ah[i], bh[j], acc[i][j], 0, 0, 0);
        acc[i][j] = __builtin_amdgcn_mfma_f32_16x16x32_f16(ah[i], bl[j], acc[i][j], 0, 0, 0);
        acc[i][j] = __builtin_amdgcn_mfma_f32_16x16x32_f16(al[i], bh[j], acc[i][j], 0, 0, 0);
      }
    __syncthreads();
  }

  const int kidx = m0 >> 9;   // 0=q 1=k 2=v (uniform per block; 128 | 512)
#pragma unroll
  for (int i = 0; i < 4; ++i) {
    float sv[4], bv[4];
#pragma unroll
    for (int r = 0; r < 4; ++r) {
      const int o = m0 + wm * 64 + i * 16 + ls * 4 + r;
      sv[r] = sA[o]; bv[r] = bA[o];
    }
    const int oc0 = (m0 & 511) + wm * 64 + i * 16 + ls * 4;
#pragma unroll
    for (int j = 0; j < 4; ++j) {
      const int n = n0 + wn * 64 + j * 16 + lr;
#pragma unroll
      for (int r = 0; r < 4; ++r) {
        const float y = fmaf(acc[i][j][r], sv[r], bv[r]);
        const size_t idx = ((size_t)b * C + oc0 + r) * NP + n;
        if (kidx == 2) {
          vw[idx] = (f16)y;
        } else {
          const signed char sgn = (signed char)((y > 0.f) - (y < 0.f));
          if (kidx == 0) qw[idx] = sgn; else kw[idx] = sgn;
        }
      }
    }
  }
}

// ---------------------------------------------------------------------------
// attn logits + softmax (fp32 VALU; exact: q,k ternary, scale 1/8 = 2^-3)
// ---------------------------------------------------------------------------
__global__ __launch_bounds__(256) void k_attn(
    const signed char* __restrict__ qw, const signed char* __restrict__ kw,
    float* __restrict__ P)
{
  const int bh = blockIdx.x;
  const int b = bh >> 3, h = bh & 7;
  const int t = threadIdx.x;
  const int tx = t & 15, ty = t >> 4;
  const int d0 = ty * 4, e0 = tx * 4;

  __shared__ float qs[64][65];
  __shared__ float ks[64][65];
  __shared__ float sa[64][65];

  const signed char* qp = qw + ((size_t)b * C + h * HD) * NP;
  const signed char* kp = kw + ((size_t)b * C + h * HD) * NP;

  float acc[4][4];
#pragma unroll
  for (int i = 0; i < 4; ++i)
#pragma unroll
    for (int j = 0; j < 4; ++j) acc[i][j] = 0.f;

  const int lrow = t >> 2;
  const int lcol = (t & 3) * 16;

  for (int c0 = 0; c0 < NP; c0 += 64) {
    int4 qv = *(const int4*)(qp + (size_t)lrow * NP + c0 + lcol);
    int4 kv = *(const int4*)(kp + (size_t)lrow * NP + c0 + lcol);
    __syncthreads();
    const signed char* qb = (const signed char*)&qv;
    const signed char* kb = (const signed char*)&kv;
#pragma unroll
    for (int i = 0; i < 16; ++i) {
      qs[lrow][lcol + i] = (float)qb[i];
      ks[lrow][lcol + i] = (float)kb[i];
    }
    __syncthreads();
#pragma unroll 4
    for (int n = 0; n < 64; ++n) {
      float qa[4], kx[4];
#pragma unroll
      for (int i = 0; i < 4; ++i) qa[i] = qs[d0 + i][n];
#pragma unroll
      for (int j = 0; j < 4; ++j) kx[j] = ks[e0 + j][n];
#pragma unroll
      for (int i = 0; i < 4; ++i)
#pragma unroll
        for (int j = 0; j < 4; ++j)
          acc[i][j] = fmaf(qa[i], kx[j], acc[i][j]);
    }
  }
  __syncthreads();
#pragma unroll
  for (int i = 0; i < 4; ++i)
#pragma unroll
    for (int j = 0; j < 4; ++j) sa[d0 + i][e0 + j] = acc[i][j];
  __syncthreads();

  if (t < 64) {
    float mx = -1e30f;
#pragma unroll 8
    for (int e = 0; e < 64; ++e) mx = fmaxf(mx, sa[t][e]);
    float sum = 0.f;
#pragma unroll 8
    for (int e = 0; e < 64; ++e) {
      const float p = expf((sa[t][e] - mx) * 0.125f);
      sa[t][e] = p;
      sum += p;
    }
    const float inv = 1.f / sum;
    float* Pp = P + (size_t)bh * HD * HD + (size_t)t * HD;
#pragma unroll 8
    for (int e = 0; e < 64; ++e) Pp[e] = sa[t][e] * inv;
  }
}

// ---------------------------------------------------------------------------
// PV: thread owns column n; writes attn-out TRANSPOSED f16 [b][n][c] for proj
// ---------------------------------------------------------------------------
__global__ __launch_bounds__(256) void k_pv(
    const float* __restrict__ P, const f16* __restrict__ vw,
    f16* __restrict__ aot)
{
  const int nc = blockIdx.x;
  const int bh = blockIdx.y;
  const int b = bh >> 3, h = bh & 7;
  const int t = threadIdx.x;

  __shared__ float ps[64][64];
  const float* Pp = P + (size_t)bh * HD * HD;
  for (int i = t; i < HD * HD; i += 256) ((float*)ps)[i] = Pp[i];
  __syncthreads();

  const int n = nc * 256 + t;
  const f16* vp = vw + ((size_t)b * C + h * HD) * NP + n;
  float vr[64];
#pragma unroll
  for (int e = 0; e < HD; ++e) vr[e] = (float)vp[(size_t)e * NP];

  f16x8 ov[8];
#pragma unroll
  for (int d = 0; d < HD; ++d) {
    float s = 0.f;
#pragma unroll
    for (int e = 0; e < HD; ++e) s = fmaf(ps[d][e], vr[e], s);
    ov[d >> 3][d & 7] = (f16)s;
  }
  f16* dst = aot + ((size_t)b * NP + n) * C + h * HD;
#pragma unroll
  for (int q = 0; q < 8; ++q) *(f16x8*)&dst[q * 8] = ov[q];
}

// ---------------------------------------------------------------------------
// proj GEMM, plain f16 MFMA + fp32 residual. Per b: [512x512]x[512x1024].
// ---------------------------------------------------------------------------
__global__ __launch_bounds__(256) void k_proj_mfma(
    const f16* __restrict__ Wph, const f16* __restrict__ aot,
    const float* __restrict__ X, float* __restrict__ out)
{
  __shared__ __align__(16) f16 Ah[128 * 32];
  __shared__ __align__(16) f16 Bh[128 * 32];

  const int t = threadIdx.x, lane = t & 63, wid = t >> 6;
  const int n0 = blockIdx.x * 128, m0 = blockIdx.y * 128, b = blockIdx.z;

  const f16* A0 = Wph + (size_t)m0 * C;
  const f16* B0 = aot + ((size_t)b * NP + n0) * C;

  f32x4 acc[4][4];
#pragma unroll
  for (int i = 0; i < 4; ++i)
#pragma unroll
    for (int j = 0; j < 4; ++j) acc[i][j] = (f32x4){0.f, 0.f, 0.f, 0.f};

  const int wm = wid >> 1, wn = wid & 1;
  const int lr = lane & 15, ls = lane >> 4;
  const int srow = wid * 16 + (lane >> 2);
  const int scol = (lane & 3) * 8;

  for (int kc = 0; kc < 512; kc += 32) {
#pragma unroll
    for (int r = 0; r < 2; ++r) {
      const size_t go = (size_t)(r * 64 + srow) * C + kc + scol;
      const int lo = (r * 64 + wid * 16) * 32;
      gld16(A0 + go, &Ah[lo]);
      gld16(B0 + go, &Bh[lo]);
    }
    __syncthreads();

    f16x8 ah[4], bh[4];
#pragma unroll
    for (int i = 0; i < 4; ++i) {
      ah[i] = *(const f16x8*)&Ah[(wm * 64 + i * 16 + lr) * 32 + ls * 8];
      bh[i] = *(const f16x8*)&Bh[(wn * 64 + i * 16 + lr) * 32 + ls * 8];
    }
#pragma unroll
    for (int i = 0; i < 4; ++i)
#pragma unroll
      for (int j = 0; j < 4; ++j)
        acc[i][j] = __builtin_amdgcn_mfma_f32_16x16x32_f16(ah[i], bh[j], acc[i][j], 0, 0, 0);
    __syncthreads();
  }

#pragma unroll
  for (int i = 0; i < 4; ++i) {
    const int oc0 = m0 + wm * 64 + i * 16 + ls * 4;
#pragma unroll
    for (int j = 0; j < 4; ++j) {
      const int n = n0 + wn * 64 + j * 16 + lr;
#pragma unroll
      for (int r = 0; r < 4; ++r) {
        const size_t idx = ((size_t)b * C + oc0 + r) * NP + n;
        out[idx] = acc[i][j][r] + X[idx];
      }
    }
  }
}

// ---------------------------------------------------------------------------
extern "C" void kernel_launch(void* const* d_in, const int* in_sizes, int n_in,
                              void* d_out, int out_size, void* d_ws, size_t ws_size,
                              hipStream_t stream)
{
  const float* x      = (const float*)d_in[0];
  const float* w_qkv  = (const float*)d_in[1];
  const float* w_proj = (const float*)d_in[2];
  const float* g      = (const float*)d_in[3];
  const float* be     = (const float*)d_in[4];
  const float* mu     = (const float*)d_in[5];
  const float* va     = (const float*)d_in[6];
  float* out = (float*)d_out;

  char* ws = (char*)d_ws;
  f16*  Whi = (f16*)(ws + OFF_WHI);
  f16*  Wlo = (f16*)(ws + OFF_WLO);
  f16*  Wph = (f16*)(ws + OFF_WPH);
  float* sA = (float*)(ws + OFF_SB);
  float* bA = sA + M3;
  f16*  XtH = (f16*)(ws + OFF_XTH);
  f16*  XtL = (f16*)(ws + OFF_XTL);
  f16*  aot = (f16*)(ws + OFF_AOT);
  signed char* qw = (signed char*)(ws + OFF_Q);
  signed char* kw = (signed char*)(ws + OFF_K);
  f16*  vw  = (f16*)(ws + OFF_V);
  float* P  = (float*)(ws + OFF_P);

  k_convW<<<dim3((M3 * C + 255) / 256), 256, 0, stream>>>(
      w_qkv, w_proj, g, be, mu, va, Whi, Wlo, Wph, sA, bA);
  k_convX<<<dim3(C / 64, NP / 64, BB), 256, 0, stream>>>(x, XtH, XtL);
  k_qkv_mfma<<<dim3(NP / 128, M3 / 128, BB), 256, 0, stream>>>(
      Whi, Wlo, XtH, XtL, sA, bA, qw, kw, vw);
  k_attn<<<dim3(BB * NH), 256, 0, stream>>>(qw, kw, P);
  k_pv<<<dim3(NP / 256, BB * NH), 256, 0, stream>>>(P, vw, aot);
  k_proj_mfma<<<dim3(NP / 128, C / 128, BB), 256, 0, stream>>>(Wph, aot, x, out);
}

// Round 3
// 152.180 us; speedup vs baseline: 4.0344x; 1.8564x over previous
//
#include <hip/hip_runtime.h>
#include <math.h>

#define BN_EPS 1e-5f

typedef _Float16 f16;
typedef _Float16 f16x4 __attribute__((ext_vector_type(4)));
typedef _Float16 f16x8 __attribute__((ext_vector_type(8)));
typedef float f32x4 __attribute__((ext_vector_type(4)));
typedef int i32x4 __attribute__((ext_vector_type(4)));

static constexpr int BB = 16;    // batch
static constexpr int C  = 512;   // channels
static constexpr int NP = 1024;  // pixels H*W
static constexpr int NH = 8;     // heads
static constexpr int HD = 64;    // head dim
static constexpr int M3 = 1536;  // 3*C

// ---- workspace layout (bytes) ----
static constexpr size_t OFF_WHI = 0;          // f16 [1536][512]
static constexpr size_t OFF_WLO = 1572864;    // f16 [1536][512]
static constexpr size_t OFF_WPH = 3145728;    // f16 [512][512]
static constexpr size_t OFF_SB  = 3670016;    // f32 s[1536], b[1536]
static constexpr size_t OFF_XTH = 3682304;    // f16 [16][1024][512]  (x^T hi)
static constexpr size_t OFF_XTL = 20459520;   // f16 [16][1024][512]  (x^T lo)
static constexpr size_t OFF_AOT = OFF_XTH;    // f16 [16][1024][512]  (aliases XTH; dead after qkv)
static constexpr size_t OFF_Q   = 37236736;   // i8  [16][512][1024]
static constexpr size_t OFF_K   = 45625344;   // i8  [16][512][1024]
static constexpr size_t OFF_VT  = 54013952;   // f16 [16][1024][512]  (v, n-major)

__device__ __forceinline__ void gld16(const void* g, void* l) {
  __builtin_amdgcn_global_load_lds(
      (const __attribute__((address_space(1))) void*)g,
      (__attribute__((address_space(3))) void*)l, 16, 0, 0);
}

// ---------------------------------------------------------------------------
// conv W: fp32 -> f16 hi/lo (qkv), f16 hi (proj), and BN scale/bias arrays
// ---------------------------------------------------------------------------
__global__ __launch_bounds__(256) void k_convW(
    const float* __restrict__ wqkv, const float* __restrict__ wproj,
    const float* __restrict__ g, const float* __restrict__ be,
    const float* __restrict__ mu, const float* __restrict__ va,
    f16* __restrict__ Whi, f16* __restrict__ Wlo, f16* __restrict__ Wph,
    float* __restrict__ sA, float* __restrict__ bA)
{
  const int i = blockIdx.x * 256 + threadIdx.x;
  if (i < M3 * C) {
    const float w = wqkv[i];
    const f16 h = (f16)w;
    Whi[i] = h;
    Wlo[i] = (f16)(w - (float)h);
  }
  if (i < C * C) Wph[i] = (f16)wproj[i];
  if (i < M3) {
    const float s = g[i] / sqrtf(va[i] + BN_EPS);
    sA[i] = s;
    bA[i] = be[i] - mu[i] * s;
  }
}

// ---------------------------------------------------------------------------
// conv X: fp32 [b][k=512][n=1024] -> f16 hi/lo transposed [b][n][k]
// ---------------------------------------------------------------------------
__global__ __launch_bounds__(256) void k_convX(
    const float* __restrict__ x, f16* __restrict__ XtH, f16* __restrict__ XtL)
{
  const int k0 = blockIdx.x * 64, n0 = blockIdx.y * 64, b = blockIdx.z;
  __shared__ float ls[64][65];
  const int t = threadIdx.x;
  const float* xp = x + ((size_t)b * C + k0) * NP + n0;
  const int c4 = (t & 15) * 4, r0 = t >> 4;
#pragma unroll
  for (int q = 0; q < 4; ++q) {
    const float4 v = *(const float4*)(xp + (size_t)(r0 + q * 16) * NP + c4);
    ls[r0 + q * 16][c4 + 0] = v.x; ls[r0 + q * 16][c4 + 1] = v.y;
    ls[r0 + q * 16][c4 + 2] = v.z; ls[r0 + q * 16][c4 + 3] = v.w;
  }
  __syncthreads();
  const int n = t >> 2, kk = (t & 3) * 16;
  f16x8 hv0 = {}, hv1 = {}, lv0 = {}, lv1 = {};
#pragma unroll
  for (int q = 0; q < 8; ++q) {
    float v = ls[kk + q][n];
    f16 h = (f16)v;
    hv0[q] = h; lv0[q] = (f16)(v - (float)h);
  }
#pragma unroll
  for (int q = 0; q < 8; ++q) {
    float v = ls[kk + 8 + q][n];
    f16 h = (f16)v;
    hv1[q] = h; lv1[q] = (f16)(v - (float)h);
  }
  const size_t o = ((size_t)b * NP + n0 + n) * C + k0 + kk;
  *(f16x8*)&XtH[o] = hv0; *(f16x8*)&XtH[o + 8] = hv1;
  *(f16x8*)&XtL[o] = lv0; *(f16x8*)&XtL[o + 8] = lv1;
}

// ---------------------------------------------------------------------------
// qkv GEMM, 2-split f16 MFMA (3 products). Per b: [1536x512]x[512x1024].
// 128x128 tile, 4 waves (2x2), 4x4 16x16x32 frags/wave, BK=32.
// Epilogue: BN, then sign->i8 (q,k) or f16 v transposed to vt[b][n][c].
// ---------------------------------------------------------------------------
__global__ __launch_bounds__(256) void k_qkv_mfma(
    const f16* __restrict__ Whi, const f16* __restrict__ Wlo,
    const f16* __restrict__ XtH, const f16* __restrict__ XtL,
    const float* __restrict__ sA, const float* __restrict__ bA,
    signed char* __restrict__ qw, signed char* __restrict__ kw,
    f16* __restrict__ vt)
{
  __shared__ __align__(16) f16 SMEM[4 * 128 * 32];
  f16* Ah = SMEM;
  f16* Al = SMEM + 4096;
  f16* Bh = SMEM + 8192;
  f16* Bl = SMEM + 12288;

  const int t = threadIdx.x, lane = t & 63, wid = t >> 6;
  const int n0 = blockIdx.x * 128, m0 = blockIdx.y * 128, b = blockIdx.z;

  const f16* A0h = Whi + (size_t)m0 * C;
  const f16* A0l = Wlo + (size_t)m0 * C;
  const f16* B0h = XtH + ((size_t)b * NP + n0) * C;
  const f16* B0l = XtL + ((size_t)b * NP + n0) * C;

  f32x4 acc[4][4];
#pragma unroll
  for (int i = 0; i < 4; ++i)
#pragma unroll
    for (int j = 0; j < 4; ++j) acc[i][j] = (f32x4){0.f, 0.f, 0.f, 0.f};

  const int wm = wid >> 1, wn = wid & 1;
  const int lr = lane & 15, ls = lane >> 4;
  const int srow = wid * 16 + (lane >> 2);
  const int scol = (lane & 3) * 8;

  for (int kc = 0; kc < 512; kc += 32) {
#pragma unroll
    for (int r = 0; r < 2; ++r) {
      const size_t go = (size_t)(r * 64 + srow) * C + kc + scol;
      const int lo = (r * 64 + wid * 16) * 32;
      gld16(A0h + go, &Ah[lo]);
      gld16(A0l + go, &Al[lo]);
      gld16(B0h + go, &Bh[lo]);
      gld16(B0l + go, &Bl[lo]);
    }
    __syncthreads();

    f16x8 ah[4], al[4], bh[4], bl[4];
#pragma unroll
    for (int i = 0; i < 4; ++i) {
      const int ao = (wm * 64 + i * 16 + lr) * 32 + ls * 8;
      ah[i] = *(const f16x8*)&Ah[ao];
      al[i] = *(const f16x8*)&Al[ao];
      const int bo = (wn * 64 + i * 16 + lr) * 32 + ls * 8;
      bh[i] = *(const f16x8*)&Bh[bo];
      bl[i] = *(const f16x8*)&Bl[bo];
    }
#pragma unroll
    for (int i = 0; i < 4; ++i)
#pragma unroll
      for (int j = 0; j < 4; ++j) {
        acc[i][j] = __builtin_amdgcn_mfma_f32_16x16x32_f16(ah[i], bh[j], acc[i][j], 0, 0, 0);
        acc[i][j] = __builtin_amdgcn_mfma_f32_16x16x32_f16(ah[i], bl[j], acc[i][j], 0, 0, 0);
        acc[i][j] = __builtin_amdgcn_mfma_f32_16x16x32_f16(al[i], bh[j], acc[i][j], 0, 0, 0);
      }
    __syncthreads();
  }

  const int kidx = m0 >> 9;   // 0=q 1=k 2=v (uniform per block)
  if (kidx != 2) {
    // q/k: BN + ternary sign -> i8 [b][c][n]
    signed char* dst0 = (kidx == 0) ? qw : kw;
#pragma unroll
    for (int i = 0; i < 4; ++i) {
      float sv[4], bv[4];
#pragma unroll
      for (int r = 0; r < 4; ++r) {
        const int o = m0 + wm * 64 + i * 16 + ls * 4 + r;
        sv[r] = sA[o]; bv[r] = bA[o];
      }
      const int oc0 = (m0 & 511) + wm * 64 + i * 16 + ls * 4;
#pragma unroll
      for (int j = 0; j < 4; ++j) {
        const int n = n0 + wn * 64 + j * 16 + lr;
#pragma unroll
        for (int r = 0; r < 4; ++r) {
          const float y = fmaf(acc[i][j][r], sv[r], bv[r]);
          dst0[((size_t)b * C + oc0 + r) * NP + n] =
              (signed char)((y > 0.f) - (y < 0.f));
        }
      }
    }
  } else {
    // v: BN + f16, transpose 64-row halves through LDS, write vt[b][n][c]
    const int c0 = m0 & 511;
    for (int hf = 0; hf < 2; ++hf) {
      __syncthreads();
      if (wn == hf) {
#pragma unroll
        for (int i = 0; i < 4; ++i) {
          float sv[4], bv[4];
#pragma unroll
          for (int r = 0; r < 4; ++r) {
            const int o = m0 + wm * 64 + i * 16 + ls * 4 + r;
            sv[r] = sA[o]; bv[r] = bA[o];
          }
#pragma unroll
          for (int j = 0; j < 4; ++j) {
            f16x4 pk;
#pragma unroll
            for (int r = 0; r < 4; ++r)
              pk[r] = (f16)fmaf(acc[i][j][r], sv[r], bv[r]);
            *(f16x4*)&SMEM[(size_t)(j * 16 + lr) * 136 + wm * 64 + i * 16 + ls * 4] = pk;
          }
        }
      }
      __syncthreads();
      const int nl = t >> 2, cc = (t & 3) * 32;
      const f16* src = &SMEM[(size_t)nl * 136 + cc];
      f16x8 r0 = *(const f16x8*)(src + 0);
      f16x8 r1 = *(const f16x8*)(src + 8);
      f16x8 r2 = *(const f16x8*)(src + 16);
      f16x8 r3 = *(const f16x8*)(src + 24);
      f16* dstv = vt + ((size_t)b * NP + n0 + hf * 64 + nl) * C + c0 + cc;
      *(f16x8*)(dstv + 0)  = r0;
      *(f16x8*)(dstv + 8)  = r1;
      *(f16x8*)(dstv + 16) = r2;
      *(f16x8*)(dstv + 24) = r3;
    }
  }
}

// ---------------------------------------------------------------------------
// Fused attention: per (b,h): S = q.k^T via i8 MFMA (exact), wave-parallel
// softmax, P -> f16 hi/lo in LDS, PV via f16 MFMA on n-major v.
// grid (2 n-halves, 128 bh), 4 waves; wave owns 16 d-rows.
// ---------------------------------------------------------------------------
__global__ __launch_bounds__(256) void k_attn_fused(
    const signed char* __restrict__ qw, const signed char* __restrict__ kw,
    const f16* __restrict__ vt, f16* __restrict__ aot)
{
  const int half = blockIdx.x;
  const int bh = blockIdx.y;
  const int b = bh >> 3, h = bh & 7;
  const int t = threadIdx.x, lane = t & 63, wid = t >> 6;
  const int dw = wid * 16;
  const int lr = lane & 15, lg = lane >> 4;

  __shared__ f16 ph[64][72];
  __shared__ f16 pl[64][72];
  __shared__ f16 sb[64][72];

  const signed char* qp = qw + ((size_t)b * C + h * HD + dw + lr) * NP;
  const signed char* kp = kw + ((size_t)b * C + h * HD + lr) * NP;

  i32x4 accS[4];
#pragma unroll
  for (int j = 0; j < 4; ++j) accS[j] = (i32x4){0, 0, 0, 0};

#pragma unroll 4
  for (int ks = 0; ks < 16; ++ks) {
    const i32x4 af = *(const i32x4*)(qp + ks * 64 + lg * 16);
#pragma unroll
    for (int j = 0; j < 4; ++j) {
      const i32x4 bf = *(const i32x4*)(kp + (size_t)(j * 16) * NP + ks * 64 + lg * 16);
      accS[j] = __builtin_amdgcn_mfma_i32_16x16x64_i8(af, bf, accS[j], 0, 0, 0);
    }
  }

  // softmax over e for rows d = dw + lg*4 + r  (16-lane groups hold a row)
#pragma unroll
  for (int r = 0; r < 4; ++r) {
    float mx = (float)accS[0][r];
#pragma unroll
    for (int j = 1; j < 4; ++j) mx = fmaxf(mx, (float)accS[j][r]);
    mx = fmaxf(mx, __shfl_xor(mx, 1));
    mx = fmaxf(mx, __shfl_xor(mx, 2));
    mx = fmaxf(mx, __shfl_xor(mx, 4));
    mx = fmaxf(mx, __shfl_xor(mx, 8));
    float pvv[4];
    float sm = 0.f;
#pragma unroll
    for (int j = 0; j < 4; ++j) {
      pvv[j] = expf(((float)accS[j][r] - mx) * 0.125f);
      sm += pvv[j];
    }
    sm += __shfl_xor(sm, 1);
    sm += __shfl_xor(sm, 2);
    sm += __shfl_xor(sm, 4);
    sm += __shfl_xor(sm, 8);
    const float inv = 1.f / sm;
    const int drow = dw + lg * 4 + r;
#pragma unroll
    for (int j = 0; j < 4; ++j) {
      const float p = pvv[j] * inv;
      const f16 hi = (f16)p;
      ph[drow][j * 16 + lr] = hi;
      pl[drow][j * 16 + lr] = (f16)(p - (float)hi);
    }
  }
  __syncthreads();

  // PV: A = P rows (wave-local), B = v (n-major), D = out[16 d][16 n]
  const f16x8 pa0h = *(const f16x8*)&ph[dw + lr][lg * 8];
  const f16x8 pa0l = *(const f16x8*)&pl[dw + lr][lg * 8];
  const f16x8 pa1h = *(const f16x8*)&ph[dw + lr][32 + lg * 8];
  const f16x8 pa1l = *(const f16x8*)&pl[dw + lr][32 + lg * 8];

  const f16* vbase = vt + (size_t)b * NP * C + h * HD;
  const int nbase = half * 512;

  for (int nc = 0; nc < 8; ++nc) {
    const int nn0 = nbase + nc * 64;
    __syncthreads();
#pragma unroll
    for (int nt = 0; nt < 4; ++nt) {
      const f16* vp = vbase + (size_t)(nn0 + nt * 16 + lr) * C + lg * 8;
      const f16x8 bv0 = *(const f16x8*)(vp);
      const f16x8 bv1 = *(const f16x8*)(vp + 32);
      f32x4 acc = (f32x4){0.f, 0.f, 0.f, 0.f};
      acc = __builtin_amdgcn_mfma_f32_16x16x32_f16(pa0h, bv0, acc, 0, 0, 0);
      acc = __builtin_amdgcn_mfma_f32_16x16x32_f16(pa0l, bv0, acc, 0, 0, 0);
      acc = __builtin_amdgcn_mfma_f32_16x16x32_f16(pa1h, bv1, acc, 0, 0, 0);
      acc = __builtin_amdgcn_mfma_f32_16x16x32_f16(pa1l, bv1, acc, 0, 0, 0);
      f16x4 pk;
#pragma unroll
      for (int r = 0; r < 4; ++r) pk[r] = (f16)acc[r];
      *(f16x4*)&sb[nt * 16 + lr][dw + lg * 4] = pk;
    }
    __syncthreads();
    const int nl = t >> 2, cc = (t & 3) * 16;
    const f16x8 o0 = *(const f16x8*)&sb[nl][cc];
    const f16x8 o1 = *(const f16x8*)&sb[nl][cc + 8];
    f16* dst = aot + ((size_t)b * NP + nn0 + nl) * C + h * HD + cc;
    *(f16x8*)(dst + 0) = o0;
    *(f16x8*)(dst + 8) = o1;
  }
}

// ---------------------------------------------------------------------------
// proj GEMM, plain f16 MFMA + fp32 residual. Per b: [512x512]x[512x1024].
// ---------------------------------------------------------------------------
__global__ __launch_bounds__(256) void k_proj_mfma(
    const f16* __restrict__ Wph, const f16* __restrict__ aot,
    const float* __restrict__ X, float* __restrict__ out)
{
  __shared__ __align__(16) f16 Ah[128 * 32];
  __shared__ __align__(16) f16 Bh[128 * 32];

  const int t = threadIdx.x, lane = t & 63, wid = t >> 6;
  const int n0 = blockIdx.x * 128, m0 = blockIdx.y * 128, b = blockIdx.z;

  const f16* A0 = Wph + (size_t)m0 * C;
  const f16* B0 = aot + ((size_t)b * NP + n0) * C;

  f32x4 acc[4][4];
#pragma unroll
  for (int i = 0; i < 4; ++i)
#pragma unroll
    for (int j = 0; j < 4; ++j) acc[i][j] = (f32x4){0.f, 0.f, 0.f, 0.f};

  const int wm = wid >> 1, wn = wid & 1;
  const int lr = lane & 15, ls = lane >> 4;
  const int srow = wid * 16 + (lane >> 2);
  const int scol = (lane & 3) * 8;

  for (int kc = 0; kc < 512; kc += 32) {
#pragma unroll
    for (int r = 0; r < 2; ++r) {
      const size_t go = (size_t)(r * 64 + srow) * C + kc + scol;
      const int lo = (r * 64 + wid * 16) * 32;
      gld16(A0 + go, &Ah[lo]);
      gld16(B0 + go, &Bh[lo]);
    }
    __syncthreads();

    f16x8 ah[4], bh[4];
#pragma unroll
    for (int i = 0; i < 4; ++i) {
      ah[i] = *(const f16x8*)&Ah[(wm * 64 + i * 16 + lr) * 32 + ls * 8];
      bh[i] = *(const f16x8*)&Bh[(wn * 64 + i * 16 + lr) * 32 + ls * 8];
    }
#pragma unroll
    for (int i = 0; i < 4; ++i)
#pragma unroll
      for (int j = 0; j < 4; ++j)
        acc[i][j] = __builtin_amdgcn_mfma_f32_16x16x32_f16(ah[i], bh[j], acc[i][j], 0, 0, 0);
    __syncthreads();
  }

#pragma unroll
  for (int i = 0; i < 4; ++i) {
    const int oc0 = m0 + wm * 64 + i * 16 + ls * 4;
#pragma unroll
    for (int j = 0; j < 4; ++j) {
      const int n = n0 + wn * 64 + j * 16 + lr;
#pragma unroll
      for (int r = 0; r < 4; ++r) {
        const size_t idx = ((size_t)b * C + oc0 + r) * NP + n;
        out[idx] = acc[i][j][r] + X[idx];
      }
    }
  }
}

// ---------------------------------------------------------------------------
extern "C" void kernel_launch(void* const* d_in, const int* in_sizes, int n_in,
                              void* d_out, int out_size, void* d_ws, size_t ws_size,
                              hipStream_t stream)
{
  const float* x      = (const float*)d_in[0];
  const float* w_qkv  = (const float*)d_in[1];
  const float* w_proj = (const float*)d_in[2];
  const float* g      = (const float*)d_in[3];
  const float* be     = (const float*)d_in[4];
  const float* mu     = (const float*)d_in[5];
  const float* va     = (const float*)d_in[6];
  float* out = (float*)d_out;

  char* ws = (char*)d_ws;
  f16*  Whi = (f16*)(ws + OFF_WHI);
  f16*  Wlo = (f16*)(ws + OFF_WLO);
  f16*  Wph = (f16*)(ws + OFF_WPH);
  float* sA = (float*)(ws + OFF_SB);
  float* bA = sA + M3;
  f16*  XtH = (f16*)(ws + OFF_XTH);
  f16*  XtL = (f16*)(ws + OFF_XTL);
  f16*  aot = (f16*)(ws + OFF_AOT);
  signed char* qw = (signed char*)(ws + OFF_Q);
  signed char* kw = (signed char*)(ws + OFF_K);
  f16*  vtw = (f16*)(ws + OFF_VT);

  k_convW<<<dim3((M3 * C + 255) / 256), 256, 0, stream>>>(
      w_qkv, w_proj, g, be, mu, va, Whi, Wlo, Wph, sA, bA);
  k_convX<<<dim3(C / 64, NP / 64, BB), 256, 0, stream>>>(x, XtH, XtL);
  k_qkv_mfma<<<dim3(NP / 128, M3 / 128, BB), 256, 0, stream>>>(
      Whi, Wlo, XtH, XtL, sA, bA, qw, kw, vtw);
  k_attn_fused<<<dim3(2, BB * NH), 256, 0, stream>>>(qw, kw, vtw, aot);
  k_proj_mfma<<<dim3(NP / 128, C / 128, BB), 256, 0, stream>>>(Wph, aot, x, out);
}

// Round 4
// 142.116 us; speedup vs baseline: 4.3201x; 1.0708x over previous
//
#include <hip/hip_runtime.h>
#include <math.h>

#define BN_EPS 1e-5f

typedef _Float16 f16;
typedef _Float16 f16x4 __attribute__((ext_vector_type(4)));
typedef _Float16 f16x8 __attribute__((ext_vector_type(8)));
typedef float f32x4 __attribute__((ext_vector_type(4)));
typedef int i32x4 __attribute__((ext_vector_type(4)));

static constexpr int BB = 16;    // batch
static constexpr int C  = 512;   // channels
static constexpr int NP = 1024;  // pixels H*W
static constexpr int NH = 8;     // heads
static constexpr int HD = 64;    // head dim
static constexpr int M3 = 1536;  // 3*C

// ---- workspace layout (bytes) ----
static constexpr size_t OFF_WHI = 0;          // f16 [1536][512]
static constexpr size_t OFF_WLO = 1572864;    // f16 [1536][512]
static constexpr size_t OFF_WPH = 3145728;    // f16 [512][512]
static constexpr size_t OFF_SB  = 3670016;    // f32 s[1536], b[1536]
static constexpr size_t OFF_XTH = 3682304;    // f16 [16][1024][512]  (x^T hi)
static constexpr size_t OFF_XTL = 20459520;   // f16 [16][1024][512]  (x^T lo)
static constexpr size_t OFF_AOT = OFF_XTH;    // f16 [16][1024][512]  (aliases XTH; dead after qkv)
static constexpr size_t OFF_Q   = 37236736;   // i8  [16][512][1024]
static constexpr size_t OFF_K   = 45625344;   // i8  [16][512][1024]
static constexpr size_t OFF_VT  = 54013952;   // f16 [16][1024][512]  (v, n-major)

__device__ __forceinline__ void gld16(const void* g, void* l) {
  __builtin_amdgcn_global_load_lds(
      (const __attribute__((address_space(1))) void*)g,
      (__attribute__((address_space(3))) void*)l, 16, 0, 0);
}

// ---------------------------------------------------------------------------
// conv W: fp32 -> f16 hi/lo (qkv), f16 hi (proj), and BN scale/bias arrays
// ---------------------------------------------------------------------------
__global__ __launch_bounds__(256) void k_convW(
    const float* __restrict__ wqkv, const float* __restrict__ wproj,
    const float* __restrict__ g, const float* __restrict__ be,
    const float* __restrict__ mu, const float* __restrict__ va,
    f16* __restrict__ Whi, f16* __restrict__ Wlo, f16* __restrict__ Wph,
    float* __restrict__ sA, float* __restrict__ bA)
{
  const int i = blockIdx.x * 256 + threadIdx.x;
  if (i < M3 * C) {
    const float w = wqkv[i];
    const f16 h = (f16)w;
    Whi[i] = h;
    Wlo[i] = (f16)(w - (float)h);
  }
  if (i < C * C) Wph[i] = (f16)wproj[i];
  if (i < M3) {
    const float s = g[i] / sqrtf(va[i] + BN_EPS);
    sA[i] = s;
    bA[i] = be[i] - mu[i] * s;
  }
}

// ---------------------------------------------------------------------------
// conv X: fp32 [b][k=512][n=1024] -> f16 hi/lo transposed [b][n][k]
// ---------------------------------------------------------------------------
__global__ __launch_bounds__(256) void k_convX(
    const float* __restrict__ x, f16* __restrict__ XtH, f16* __restrict__ XtL)
{
  const int k0 = blockIdx.x * 64, n0 = blockIdx.y * 64, b = blockIdx.z;
  __shared__ float ls[64][65];
  const int t = threadIdx.x;
  const float* xp = x + ((size_t)b * C + k0) * NP + n0;
  const int c4 = (t & 15) * 4, r0 = t >> 4;
#pragma unroll
  for (int q = 0; q < 4; ++q) {
    const float4 v = *(const float4*)(xp + (size_t)(r0 + q * 16) * NP + c4);
    ls[r0 + q * 16][c4 + 0] = v.x; ls[r0 + q * 16][c4 + 1] = v.y;
    ls[r0 + q * 16][c4 + 2] = v.z; ls[r0 + q * 16][c4 + 3] = v.w;
  }
  __syncthreads();
  const int n = t >> 2, kk = (t & 3) * 16;
  f16x8 hv0 = {}, hv1 = {}, lv0 = {}, lv1 = {};
#pragma unroll
  for (int q = 0; q < 8; ++q) {
    float v = ls[kk + q][n];
    f16 h = (f16)v;
    hv0[q] = h; lv0[q] = (f16)(v - (float)h);
  }
#pragma unroll
  for (int q = 0; q < 8; ++q) {
    float v = ls[kk + 8 + q][n];
    f16 h = (f16)v;
    hv1[q] = h; lv1[q] = (f16)(v - (float)h);
  }
  const size_t o = ((size_t)b * NP + n0 + n) * C + k0 + kk;
  *(f16x8*)&XtH[o] = hv0; *(f16x8*)&XtH[o + 8] = hv1;
  *(f16x8*)&XtL[o] = lv0; *(f16x8*)&XtL[o + 8] = lv1;
}

// ---------------------------------------------------------------------------
// qkv GEMM. Per b: [1536x512]x[512x1024]. 128x128 tile, 4 waves (2x2),
// 4x4 16x16x32 frags/wave, BK=32.
//   q/k rows (m0 < 1024): 2-split f16, 3 MFMA products (fp32-class, feeds sign)
//   v rows   (m0 >= 1024): single f16 product (v is f16-rounded anyway)
// Epilogue: BN, then sign->i8 (q,k) or f16 v transposed to vt[b][n][c].
// ---------------------------------------------------------------------------
__global__ __launch_bounds__(256) void k_qkv_mfma(
    const f16* __restrict__ Whi, const f16* __restrict__ Wlo,
    const f16* __restrict__ XtH, const f16* __restrict__ XtL,
    const float* __restrict__ sA, const float* __restrict__ bA,
    signed char* __restrict__ qw, signed char* __restrict__ kw,
    f16* __restrict__ vt)
{
  __shared__ __align__(16) f16 SMEM[4 * 128 * 32];
  f16* Ah = SMEM;
  f16* Al = SMEM + 4096;
  f16* Bh = SMEM + 8192;
  f16* Bl = SMEM + 12288;

  const int t = threadIdx.x, lane = t & 63, wid = t >> 6;
  const int n0 = blockIdx.x * 128, m0 = blockIdx.y * 128, b = blockIdx.z;

  const f16* A0h = Whi + (size_t)m0 * C;
  const f16* A0l = Wlo + (size_t)m0 * C;
  const f16* B0h = XtH + ((size_t)b * NP + n0) * C;
  const f16* B0l = XtL + ((size_t)b * NP + n0) * C;

  f32x4 acc[4][4];
#pragma unroll
  for (int i = 0; i < 4; ++i)
#pragma unroll
    for (int j = 0; j < 4; ++j) acc[i][j] = (f32x4){0.f, 0.f, 0.f, 0.f};

  const int wm = wid >> 1, wn = wid & 1;
  const int lr = lane & 15, ls = lane >> 4;
  const int srow = wid * 16 + (lane >> 2);
  const int scol = (lane & 3) * 8;

  const int kidx = m0 >> 9;   // 0=q 1=k 2=v (uniform per block)

  if (kidx == 2) {
    // --- v: single-product f16 GEMM ---
    for (int kc = 0; kc < 512; kc += 32) {
#pragma unroll
      for (int r = 0; r < 2; ++r) {
        const size_t go = (size_t)(r * 64 + srow) * C + kc + scol;
        const int lo = (r * 64 + wid * 16) * 32;
        gld16(A0h + go, &Ah[lo]);
        gld16(B0h + go, &Bh[lo]);
      }
      __syncthreads();
      f16x8 ah[4], bh[4];
#pragma unroll
      for (int i = 0; i < 4; ++i) {
        ah[i] = *(const f16x8*)&Ah[(wm * 64 + i * 16 + lr) * 32 + ls * 8];
        bh[i] = *(const f16x8*)&Bh[(wn * 64 + i * 16 + lr) * 32 + ls * 8];
      }
#pragma unroll
      for (int i = 0; i < 4; ++i)
#pragma unroll
        for (int j = 0; j < 4; ++j)
          acc[i][j] = __builtin_amdgcn_mfma_f32_16x16x32_f16(ah[i], bh[j], acc[i][j], 0, 0, 0);
      __syncthreads();
    }
  } else {
    // --- q/k: 2-split, 3 products ---
    for (int kc = 0; kc < 512; kc += 32) {
#pragma unroll
      for (int r = 0; r < 2; ++r) {
        const size_t go = (size_t)(r * 64 + srow) * C + kc + scol;
        const int lo = (r * 64 + wid * 16) * 32;
        gld16(A0h + go, &Ah[lo]);
        gld16(A0l + go, &Al[lo]);
        gld16(B0h + go, &Bh[lo]);
        gld16(B0l + go, &Bl[lo]);
      }
      __syncthreads();

      f16x8 ah[4], al[4], bh[4], bl[4];
#pragma unroll
      for (int i = 0; i < 4; ++i) {
        const int ao = (wm * 64 + i * 16 + lr) * 32 + ls * 8;
        ah[i] = *(const f16x8*)&Ah[ao];
        al[i] = *(const f16x8*)&Al[ao];
        const int bo = (wn * 64 + i * 16 + lr) * 32 + ls * 8;
        bh[i] = *(const f16x8*)&Bh[bo];
        bl[i] = *(const f16x8*)&Bl[bo];
      }
#pragma unroll
      for (int i = 0; i < 4; ++i)
#pragma unroll
        for (int j = 0; j < 4; ++j) {
          acc[i][j] = __builtin_amdgcn_mfma_f32_16x16x32_f16(ah[i], bh[j], acc[i][j], 0, 0, 0);
          acc[i][j] = __builtin_amdgcn_mfma_f32_16x16x32_f16(ah[i], bl[j], acc[i][j], 0, 0, 0);
          acc[i][j] = __builtin_amdgcn_mfma_f32_16x16x32_f16(al[i], bh[j], acc[i][j], 0, 0, 0);
        }
      __syncthreads();
    }
  }

  if (kidx != 2) {
    // q/k: BN + ternary sign -> i8 [b][c][n]
    signed char* dst0 = (kidx == 0) ? qw : kw;
#pragma unroll
    for (int i = 0; i < 4; ++i) {
      float sv[4], bv[4];
#pragma unroll
      for (int r = 0; r < 4; ++r) {
        const int o = m0 + wm * 64 + i * 16 + ls * 4 + r;
        sv[r] = sA[o]; bv[r] = bA[o];
      }
      const int oc0 = (m0 & 511) + wm * 64 + i * 16 + ls * 4;
#pragma unroll
      for (int j = 0; j < 4; ++j) {
        const int n = n0 + wn * 64 + j * 16 + lr;
#pragma unroll
        for (int r = 0; r < 4; ++r) {
          const float y = fmaf(acc[i][j][r], sv[r], bv[r]);
          dst0[((size_t)b * C + oc0 + r) * NP + n] =
              (signed char)((y > 0.f) - (y < 0.f));
        }
      }
    }
  } else {
    // v: BN + f16, transpose 64-row halves through LDS, write vt[b][n][c]
    const int c0 = m0 & 511;
    for (int hf = 0; hf < 2; ++hf) {
      __syncthreads();
      if (wn == hf) {
#pragma unroll
        for (int i = 0; i < 4; ++i) {
          float sv[4], bv[4];
#pragma unroll
          for (int r = 0; r < 4; ++r) {
            const int o = m0 + wm * 64 + i * 16 + ls * 4 + r;
            sv[r] = sA[o]; bv[r] = bA[o];
          }
#pragma unroll
          for (int j = 0; j < 4; ++j) {
            f16x4 pk;
#pragma unroll
            for (int r = 0; r < 4; ++r)
              pk[r] = (f16)fmaf(acc[i][j][r], sv[r], bv[r]);
            *(f16x4*)&SMEM[(size_t)(j * 16 + lr) * 136 + wm * 64 + i * 16 + ls * 4] = pk;
          }
        }
      }
      __syncthreads();
      const int nl = t >> 2, cc = (t & 3) * 32;
      const f16* src = &SMEM[(size_t)nl * 136 + cc];
      f16x8 r0 = *(const f16x8*)(src + 0);
      f16x8 r1 = *(const f16x8*)(src + 8);
      f16x8 r2 = *(const f16x8*)(src + 16);
      f16x8 r3 = *(const f16x8*)(src + 24);
      f16* dstv = vt + ((size_t)b * NP + n0 + hf * 64 + nl) * C + c0 + cc;
      *(f16x8*)(dstv + 0)  = r0;
      *(f16x8*)(dstv + 8)  = r1;
      *(f16x8*)(dstv + 16) = r2;
      *(f16x8*)(dstv + 24) = r3;
    }
  }
}

// ---------------------------------------------------------------------------
// Fused attention: per (b,h): S = q.k^T via i8 MFMA (exact), wave-parallel
// softmax, P -> f16 hi/lo in LDS, PV via f16 MFMA on n-major v.
// grid (2 n-halves, 128 bh), 4 waves; wave owns 16 d-rows.
// ---------------------------------------------------------------------------
__global__ __launch_bounds__(256) void k_attn_fused(
    const signed char* __restrict__ qw, const signed char* __restrict__ kw,
    const f16* __restrict__ vt, f16* __restrict__ aot)
{
  const int half = blockIdx.x;
  const int bh = blockIdx.y;
  const int b = bh >> 3, h = bh & 7;
  const int t = threadIdx.x, lane = t & 63, wid = t >> 6;
  const int dw = wid * 16;
  const int lr = lane & 15, lg = lane >> 4;

  __shared__ f16 ph[64][72];
  __shared__ f16 pl[64][72];
  __shared__ f16 sb[64][72];

  const signed char* qp = qw + ((size_t)b * C + h * HD + dw + lr) * NP;
  const signed char* kp = kw + ((size_t)b * C + h * HD + lr) * NP;

  i32x4 accS[4];
#pragma unroll
  for (int j = 0; j < 4; ++j) accS[j] = (i32x4){0, 0, 0, 0};

#pragma unroll 4
  for (int ks = 0; ks < 16; ++ks) {
    const i32x4 af = *(const i32x4*)(qp + ks * 64 + lg * 16);
#pragma unroll
    for (int j = 0; j < 4; ++j) {
      const i32x4 bf = *(const i32x4*)(kp + (size_t)(j * 16) * NP + ks * 64 + lg * 16);
      accS[j] = __builtin_amdgcn_mfma_i32_16x16x64_i8(af, bf, accS[j], 0, 0, 0);
    }
  }

  // softmax over e for rows d = dw + lg*4 + r  (16-lane groups hold a row)
#pragma unroll
  for (int r = 0; r < 4; ++r) {
    float mx = (float)accS[0][r];
#pragma unroll
    for (int j = 1; j < 4; ++j) mx = fmaxf(mx, (float)accS[j][r]);
    mx = fmaxf(mx, __shfl_xor(mx, 1));
    mx = fmaxf(mx, __shfl_xor(mx, 2));
    mx = fmaxf(mx, __shfl_xor(mx, 4));
    mx = fmaxf(mx, __shfl_xor(mx, 8));
    float pvv[4];
    float sm = 0.f;
#pragma unroll
    for (int j = 0; j < 4; ++j) {
      pvv[j] = expf(((float)accS[j][r] - mx) * 0.125f);
      sm += pvv[j];
    }
    sm += __shfl_xor(sm, 1);
    sm += __shfl_xor(sm, 2);
    sm += __shfl_xor(sm, 4);
    sm += __shfl_xor(sm, 8);
    const float inv = 1.f / sm;
    const int drow = dw + lg * 4 + r;
#pragma unroll
    for (int j = 0; j < 4; ++j) {
      const float p = pvv[j] * inv;
      const f16 hi = (f16)p;
      ph[drow][j * 16 + lr] = hi;
      pl[drow][j * 16 + lr] = (f16)(p - (float)hi);
    }
  }
  __syncthreads();

  // PV: A = P rows (wave-local), B = v (n-major), D = out[16 d][16 n]
  const f16x8 pa0h = *(const f16x8*)&ph[dw + lr][lg * 8];
  const f16x8 pa0l = *(const f16x8*)&pl[dw + lr][lg * 8];
  const f16x8 pa1h = *(const f16x8*)&ph[dw + lr][32 + lg * 8];
  const f16x8 pa1l = *(const f16x8*)&pl[dw + lr][32 + lg * 8];

  const f16* vbase = vt + (size_t)b * NP * C + h * HD;
  const int nbase = half * 512;

  for (int nc = 0; nc < 8; ++nc) {
    const int nn0 = nbase + nc * 64;
    __syncthreads();
#pragma unroll
    for (int nt = 0; nt < 4; ++nt) {
      const f16* vp = vbase + (size_t)(nn0 + nt * 16 + lr) * C + lg * 8;
      const f16x8 bv0 = *(const f16x8*)(vp);
      const f16x8 bv1 = *(const f16x8*)(vp + 32);
      f32x4 acc = (f32x4){0.f, 0.f, 0.f, 0.f};
      acc = __builtin_amdgcn_mfma_f32_16x16x32_f16(pa0h, bv0, acc, 0, 0, 0);
      acc = __builtin_amdgcn_mfma_f32_16x16x32_f16(pa0l, bv0, acc, 0, 0, 0);
      acc = __builtin_amdgcn_mfma_f32_16x16x32_f16(pa1h, bv1, acc, 0, 0, 0);
      acc = __builtin_amdgcn_mfma_f32_16x16x32_f16(pa1l, bv1, acc, 0, 0, 0);
      f16x4 pk;
#pragma unroll
      for (int r = 0; r < 4; ++r) pk[r] = (f16)acc[r];
      *(f16x4*)&sb[nt * 16 + lr][dw + lg * 4] = pk;
    }
    __syncthreads();
    const int nl = t >> 2, cc = (t & 3) * 16;
    const f16x8 o0 = *(const f16x8*)&sb[nl][cc];
    const f16x8 o1 = *(const f16x8*)&sb[nl][cc + 8];
    f16* dst = aot + ((size_t)b * NP + nn0 + nl) * C + h * HD + cc;
    *(f16x8*)(dst + 0) = o0;
    *(f16x8*)(dst + 8) = o1;
  }
}

// ---------------------------------------------------------------------------
// proj GEMM, plain f16 MFMA + fp32 residual. Per b: [512x512]x[512x1024].
// ---------------------------------------------------------------------------
__global__ __launch_bounds__(256) void k_proj_mfma(
    const f16* __restrict__ Wph, const f16* __restrict__ aot,
    const float* __restrict__ X, float* __restrict__ out)
{
  __shared__ __align__(16) f16 Ah[128 * 32];
  __shared__ __align__(16) f16 Bh[128 * 32];

  const int t = threadIdx.x, lane = t & 63, wid = t >> 6;
  const int n0 = blockIdx.x * 128, m0 = blockIdx.y * 128, b = blockIdx.z;

  const f16* A0 = Wph + (size_t)m0 * C;
  const f16* B0 = aot + ((size_t)b * NP + n0) * C;

  f32x4 acc[4][4];
#pragma unroll
  for (int i = 0; i < 4; ++i)
#pragma unroll
    for (int j = 0; j < 4; ++j) acc[i][j] = (f32x4){0.f, 0.f, 0.f, 0.f};

  const int wm = wid >> 1, wn = wid & 1;
  const int lr = lane & 15, ls = lane >> 4;
  const int srow = wid * 16 + (lane >> 2);
  const int scol = (lane & 3) * 8;

  for (int kc = 0; kc < 512; kc += 32) {
#pragma unroll
    for (int r = 0; r < 2; ++r) {
      const size_t go = (size_t)(r * 64 + srow) * C + kc + scol;
      const int lo = (r * 64 + wid * 16) * 32;
      gld16(A0 + go, &Ah[lo]);
      gld16(B0 + go, &Bh[lo]);
    }
    __syncthreads();

    f16x8 ah[4], bh[4];
#pragma unroll
    for (int i = 0; i < 4; ++i) {
      ah[i] = *(const f16x8*)&Ah[(wm * 64 + i * 16 + lr) * 32 + ls * 8];
      bh[i] = *(const f16x8*)&Bh[(wn * 64 + i * 16 + lr) * 32 + ls * 8];
    }
#pragma unroll
    for (int i = 0; i < 4; ++i)
#pragma unroll
      for (int j = 0; j < 4; ++j)
        acc[i][j] = __builtin_amdgcn_mfma_f32_16x16x32_f16(ah[i], bh[j], acc[i][j], 0, 0, 0);
    __syncthreads();
  }

#pragma unroll
  for (int i = 0; i < 4; ++i) {
    const int oc0 = m0 + wm * 64 + i * 16 + ls * 4;
#pragma unroll
    for (int j = 0; j < 4; ++j) {
      const int n = n0 + wn * 64 + j * 16 + lr;
#pragma unroll
      for (int r = 0; r < 4; ++r) {
        const size_t idx = ((size_t)b * C + oc0 + r) * NP + n;
        out[idx] = acc[i][j][r] + X[idx];
      }
    }
  }
}

// ---------------------------------------------------------------------------
extern "C" void kernel_launch(void* const* d_in, const int* in_sizes, int n_in,
                              void* d_out, int out_size, void* d_ws, size_t ws_size,
                              hipStream_t stream)
{
  const float* x      = (const float*)d_in[0];
  const float* w_qkv  = (const float*)d_in[1];
  const float* w_proj = (const float*)d_in[2];
  const float* g      = (const float*)d_in[3];
  const float* be     = (const float*)d_in[4];
  const float* mu     = (const float*)d_in[5];
  const float* va     = (const float*)d_in[6];
  float* out = (float*)d_out;

  char* ws = (char*)d_ws;
  f16*  Whi = (f16*)(ws + OFF_WHI);
  f16*  Wlo = (f16*)(ws + OFF_WLO);
  f16*  Wph = (f16*)(ws + OFF_WPH);
  float* sA = (float*)(ws + OFF_SB);
  float* bA = sA + M3;
  f16*  XtH = (f16*)(ws + OFF_XTH);
  f16*  XtL = (f16*)(ws + OFF_XTL);
  f16*  aot = (f16*)(ws + OFF_AOT);
  signed char* qw = (signed char*)(ws + OFF_Q);
  signed char* kw = (signed char*)(ws + OFF_K);
  f16*  vtw = (f16*)(ws + OFF_VT);

  k_convW<<<dim3((M3 * C + 255) / 256), 256, 0, stream>>>(
      w_qkv, w_proj, g, be, mu, va, Whi, Wlo, Wph, sA, bA);
  k_convX<<<dim3(C / 64, NP / 64, BB), 256, 0, stream>>>(x, XtH, XtL);
  k_qkv_mfma<<<dim3(NP / 128, M3 / 128, BB), 256, 0, stream>>>(
      Whi, Wlo, XtH, XtL, sA, bA, qw, kw, vtw);
  k_attn_fused<<<dim3(2, BB * NH), 256, 0, stream>>>(qw, kw, vtw, aot);
  k_proj_mfma<<<dim3(NP / 128, C / 128, BB), 256, 0, stream>>>(Wph, aot, x, out);
}